// Round 4
// baseline (238.371 us; speedup 1.0000x reference)
//
#include <hip/hip_runtime.h>

// Problem constants (from reference): N=512, OBS=32, H=128, M=128, L=3
#define NA 512
#define NOBS 32
#define NH 128

typedef const float* fp32p;
typedef __attribute__((ext_vector_type(8))) short bf16x8;
typedef __attribute__((ext_vector_type(4))) short bf16x4;
typedef __attribute__((ext_vector_type(4))) float f32x4;

// packed 2xf32 -> 2xbf16 (RNE) in one instruction (gfx950); lo -> bits[15:0]
__device__ __forceinline__ unsigned cvt_pk_bf16(float lo, float hi) {
    unsigned r;
    asm("v_cvt_pk_bf16_f32 %0, %1, %2" : "=v"(r) : "v"(lo), "v"(hi));
    return r;
}

__device__ __forceinline__ bf16x8 wfrag_f4(const float* p) {  // 16B-aligned
    float4 u = *(const float4*)p;
    float4 v = *(const float4*)(p + 4);
    union { unsigned w[4]; bf16x8 f; } r;
    r.w[0] = cvt_pk_bf16(u.x, u.y);
    r.w[1] = cvt_pk_bf16(u.z, u.w);
    r.w[2] = cvt_pk_bf16(v.x, v.y);
    r.w[3] = cvt_pk_bf16(v.z, v.w);
    return r.f;
}

// K=16 bf16 MFMA: name differs across ROCm versions; guard with __has_builtin.
#if __has_builtin(__builtin_amdgcn_mfma_f32_16x16x16bf16_1k)
#define MFMA_K16(A, B, C) __builtin_amdgcn_mfma_f32_16x16x16bf16_1k(A, B, C, 0, 0, 0)
#elif __has_builtin(__builtin_amdgcn_mfma_f32_16x16x16_bf16)
#define MFMA_K16(A, B, C) __builtin_amdgcn_mfma_f32_16x16x16_bf16(A, B, C, 0, 0, 0)
#else
__device__ __forceinline__ f32x4 mfma_k16_asm(bf16x4 a, bf16x4 b, f32x4 c) {
    f32x4 d;
    asm volatile("v_mfma_f32_16x16x16_bf16 %0, %1, %2, %3\n\t"
                 "s_nop 7\n\ts_nop 7\n\ts_nop 7"
                 : "=v"(d) : "v"(a), "v"(b), "v"(c));
    return d;
}
#define MFMA_K16(A, B, C) mfma_k16_asm(A, B, C)
#endif

#define HSTR 136   // LDS row stride (shorts) for 128-wide bf16 tiles

// ----------------------------------------- fused encoder + layer-0 ab ------
// grid 512 x 512 (proven): GEMV phases, 4 lanes per output row.
__global__ __launch_bounds__(512) void enc_ab_kernel(
    fp32p obs, fp32p eW1, fp32p eb1, fp32p eW2, fp32p eb2, fp32p eW3, fp32p eb3,
    fp32p mW1, float* __restrict__ z, float* __restrict__ A, float* __restrict__ B) {
    const int i = blockIdx.x;
    const int t = threadIdx.x;
    const int nn = t >> 2;   // output row 0..127
    const int ks = t & 3;    // k-segment

    __shared__ float xs0[NOBS];
    __shared__ float part[4 * NH];
    __shared__ float part2[4 * NH];
    __shared__ float hx[NH], hy[NH], zz[NH];

    if (t < NOBS) xs0[t] = obs[(size_t)i * NOBS + t];
    __syncthreads();
    // L1: K=32 (8 k per lane)
    {
        const float* wr = eW1 + (size_t)nn * NOBS + ks * 8;
        const float4 w0 = *(const float4*)wr;
        const float4 w1 = *(const float4*)(wr + 4);
        const float4 x0 = *(const float4*)&xs0[ks * 8];
        const float4 x1 = *(const float4*)&xs0[ks * 8 + 4];
        part[ks * NH + nn] = w0.x * x0.x + w0.y * x0.y + w0.z * x0.z + w0.w * x0.w +
                             w1.x * x1.x + w1.y * x1.y + w1.z * x1.z + w1.w * x1.w;
    }
    __syncthreads();
    if (t < NH)
        hx[t] = fmaxf(eb1[t] + part[t] + part[NH + t] + part[2 * NH + t] + part[3 * NH + t], 0.f);
    __syncthreads();
    // L2: K=128
    {
        const float* wr = eW2 + (size_t)nn * NH + ks * 4;
        float p = 0.f;
        #pragma unroll
        for (int it = 0; it < 8; ++it) {
            const float4 wv = *(const float4*)(wr + it * 16);
            const float4 xv = *(const float4*)&hx[it * 16 + ks * 4];
            p += wv.x * xv.x + wv.y * xv.y + wv.z * xv.z + wv.w * xv.w;
        }
        part[ks * NH + nn] = p;
    }
    __syncthreads();
    if (t < NH)
        hy[t] = fmaxf(eb2[t] + part[t] + part[NH + t] + part[2 * NH + t] + part[3 * NH + t], 0.f);
    __syncthreads();
    // L3: K=128, no relu -> z
    {
        const float* wr = eW3 + (size_t)nn * NH + ks * 4;
        float p = 0.f;
        #pragma unroll
        for (int it = 0; it < 8; ++it) {
            const float4 wv = *(const float4*)(wr + it * 16);
            const float4 xv = *(const float4*)&hy[it * 16 + ks * 4];
            p += wv.x * xv.x + wv.y * xv.y + wv.z * xv.z + wv.w * xv.w;
        }
        part[ks * NH + nn] = p;
    }
    __syncthreads();
    if (t < NH) {
        const float v = eb3[t] + part[t] + part[NH + t] + part[2 * NH + t] + part[3 * NH + t];
        z[(size_t)i * NH + t] = v;
        zz[t] = v;
    }
    __syncthreads();
    // ab layer 0 (K=128, row stride 257 -> dword loads)
    {
        const float* pr = mW1 + (size_t)nn * 257;
        float pa = 0.f, pb = 0.f;
        #pragma unroll
        for (int it = 0; it < 8; ++it) {
            #pragma unroll
            for (int j = 0; j < 4; ++j) {
                const int k = it * 16 + ks * 4 + j;
                const float x = zz[k];
                pa += x * pr[k];
                pb += x * pr[NH + k];
            }
        }
        part[ks * NH + nn] = pa;
        part2[ks * NH + nn] = pb;
    }
    __syncthreads();
    if (t < NH) {
        A[(size_t)i * NH + t] = part[t] + part[NH + t] + part[2 * NH + t] + part[3 * NH + t];
        B[(size_t)i * NH + t] = part2[t] + part2[NH + t] + part2[2 * NH + t] + part2[3 * NH + t];
    }
}

// -------------------------------------- fused message + update + next-ab ----
// One block per agent i; 8 waves. R0-proven skeleton (build / GEMM1 per-jt,
// HSTR=136, 16-col wave slices) but GEMM2 is FUSED INTO REGISTERS:
//   GEMM1 computed operand-swapped: acc1 = mfma(w2f, h1_frag) gives h2^T
//   fragments in exactly the B-frag layout of mfma_16x16x16 (K=16 = this
//   wave's 16-col slice of the M dimension). GEMM2 then runs as 8 register
//   MFMAs per jt against a preloaded W3 slice; per-wave k-partials of
//   msum accumulate in 32 VGPRs and are reduced once at the end.
// Eliminates: all h2s LDS writes+reads (-50% LDS traffic, the measured
// bottleneck), 1 of 3 barriers/chunk, and the per-element diag mask
// (diagonal excluded exactly by zeroing the j==i lane's B-frag).
__global__ __launch_bounds__(512, 2) void msg_upd_kernel(
    const float* __restrict__ A, const float* __restrict__ B,
    fp32p pos, const float* __restrict__ zin,
    fp32p W1l, fp32p b1, fp32p W2, fp32p b2, fp32p W3, fp32p b3,
    fp32p uW1, fp32p ub1, fp32p uW2, fp32p ub2, fp32p uW3, fp32p ub3,
    fp32p msgW1n, int do_ab,
    float* __restrict__ zout, float* __restrict__ An, float* __restrict__ Bn) {
    const int i = blockIdx.x;
    const int t = threadIdx.x;
    const int lane = t & 63;
    const int w = t >> 6;
    const int q = lane >> 4;
    const int c = lane & 15;
    const int ncol = w * 16 + c;

    __shared__ short h1s[128 * HSTR];  // 34816 B
    __shared__ float distrow[NA];
    __shared__ float amrow[NH];        // A_i + b1 folded
    __shared__ float wdsr[NH];
    __shared__ float xs2[2 * NH];      // [z_i | msum_i]
    __shared__ float part[4 * NH];
    __shared__ float part2[4 * NH];
    __shared__ float partsum[8 * NH];  // per-wave GEMM2 k-partials
    __shared__ float hx[NH], hy[NH], hz[NH];

    if (t < NH) {
        amrow[t] = A[i * NH + t] + b1[t];
        wdsr[t]  = W1l[t * 257 + 256];
        xs2[t] = zin[(size_t)i * NH + t];
    }
    {
        const float2 pi = *(const float2*)&pos[2 * i];
        const float2 pj = *(const float2*)&pos[2 * t];
        const float dx = pi.x - pj.x, dy = pi.y - pj.y;
        const float s = dx * dx + dy * dy;
        distrow[t] = (t == i) ? 0.0f : sqrtf(s);
    }

    // W2 fragment (A-operand of swapped GEMM1): lane c -> W2 row ncol,
    // k = kb*32 + q*8 + e  (same layout as R0-proven w2f)
    bf16x8 w2f[4];
    {
        const float* w2r = W2 + (size_t)ncol * NH + q * 8;
        #pragma unroll
        for (int kb = 0; kb < 4; ++kb) w2f[kb] = wfrag_f4(w2r + kb * 32);
    }
    // W3 slice (A-operand of GEMM2, K=16 = this wave's 16 cols):
    // lane c -> W3 row n2t*16+c, k = q*4 + e  (4 consecutive cols)
    bf16x4 w3s[8];
    #pragma unroll
    for (int n2t = 0; n2t < 8; ++n2t) {
        const float4 wv = *(const float4*)(W3 + (size_t)(n2t * 16 + c) * NH + w * 16 + q * 4);
        union { unsigned u[2]; bf16x4 v; } r;
        r.u[0] = cvt_pk_bf16(wv.x, wv.y);
        r.u[1] = cvt_pk_bf16(wv.z, wv.w);
        w3s[n2t] = r.v;
    }
    const float4 b2q = *(const float4*)(b2 + w * 16 + q * 4);

    f32x4 acc2[8];
    #pragma unroll
    for (int n2t = 0; n2t < 8; ++n2t) acc2[n2t] = (f32x4){0.f, 0.f, 0.f, 0.f};

    const int m2 = lane * 2;

    for (int c4 = 0; c4 < 4; ++c4) {
        const int j0 = c4 * 128;
        __syncthreads();

        // ---- build h1 chunk (128 x 128) as bf16 ----
        {
            const float am0 = amrow[m2],     am1 = amrow[m2 + 1];
            const float wd0 = wdsr[m2],      wd1 = wdsr[m2 + 1];
            #pragma unroll
            for (int rr = 0; rr < 16; ++rr) {
                const int row = rr * 8 + w;
                const int jg  = j0 + row;
                const float2 bv = *(const float2*)&B[(size_t)jg * NH + m2];
                const float d = distrow[jg];
                const float v0 = fmaxf(fmaf(d, wd0, am0 + bv.x), 0.0f);
                const float v1 = fmaxf(fmaf(d, wd1, am1 + bv.y), 0.0f);
                *(unsigned*)&h1s[row * HSTR + m2] = cvt_pk_bf16(v0, v1);
            }
        }
        __syncthreads();

        // ---- fused GEMM1 (swapped) + register GEMM2 ----
        #pragma unroll
        for (int jt = 0; jt < 8; ++jt) {
            f32x4 acc1 = {0.f, 0.f, 0.f, 0.f};
            const short* arow = &h1s[(jt * 16 + c) * HSTR + q * 8];
            #pragma unroll
            for (int kb = 0; kb < 4; ++kb) {
                bf16x8 a = *(const bf16x8*)(arow + kb * 32);
                // swapped: A=w2f (m-dim = n), B=h1 frag (n-dim = j)
                acc1 = __builtin_amdgcn_mfma_f32_16x16x32_bf16(w2f[kb], a, acc1, 0, 0, 0);
            }
            // acc1[e] = pre-h2[n = w*16+4q+e][j = jt*16+c]
            // -> bfrag = B-operand of K=16 MFMA: B[k_local=4q+e][j=c]
            const float v0 = fmaxf(acc1[0] + b2q.x, 0.f);
            const float v1 = fmaxf(acc1[1] + b2q.y, 0.f);
            const float v2 = fmaxf(acc1[2] + b2q.z, 0.f);
            const float v3 = fmaxf(acc1[3] + b2q.w, 0.f);
            unsigned u0 = cvt_pk_bf16(v0, v1);
            unsigned u1 = cvt_pk_bf16(v2, v3);
            if (j0 + jt * 16 + c == i) { u0 = 0u; u1 = 0u; }  // exact diag mask
            union { unsigned u[2]; bf16x4 v; } bf;
            bf.u[0] = u0; bf.u[1] = u1;
            #pragma unroll
            for (int n2t = 0; n2t < 8; ++n2t)
                acc2[n2t] = MFMA_K16(w3s[n2t], bf.v, acc2[n2t]);
        }
    }

    // ---- reduce acc2: sum over j (c-lanes), publish per-wave k-partials ----
    #pragma unroll
    for (int n2t = 0; n2t < 8; ++n2t) {
        #pragma unroll
        for (int r = 0; r < 4; ++r) {
            float v = acc2[n2t][r];
            v += __shfl_xor(v, 1, 64);
            v += __shfl_xor(v, 2, 64);
            v += __shfl_xor(v, 4, 64);
            v += __shfl_xor(v, 8, 64);
            if (c == 0) partsum[w * NH + n2t * 16 + q * 4 + r] = v;
        }
    }
    __syncthreads();
    if (t < NH) {
        float s = 0.f;
        #pragma unroll
        for (int ww = 0; ww < 8; ++ww) s += partsum[ww * NH + t];
        xs2[NH + t] = s + 511.0f * b3[t];
    }
    __syncthreads();

    // ---- tail: update MLP (fp32 GEMV, 4 lanes per output row) ----
    const int nn = t >> 2;   // output row 0..127
    const int ks = t & 3;    // k-segment
    // L1: K=256
    {
        const float* wr = uW1 + (size_t)nn * 256 + ks * 4;
        float p = 0.f;
        #pragma unroll
        for (int it = 0; it < 16; ++it) {
            const float4 wv = *(const float4*)(wr + it * 16);
            const float4 xv = *(const float4*)&xs2[it * 16 + ks * 4];
            p += wv.x * xv.x + wv.y * xv.y + wv.z * xv.z + wv.w * xv.w;
        }
        part[ks * NH + nn] = p;
    }
    __syncthreads();
    if (t < NH)
        hx[t] = fmaxf(ub1[t] + part[t] + part[NH + t] + part[2 * NH + t] + part[3 * NH + t], 0.f);
    __syncthreads();
    // L2: K=128
    {
        const float* wr = uW2 + (size_t)nn * NH + ks * 4;
        float p = 0.f;
        #pragma unroll
        for (int it = 0; it < 8; ++it) {
            const float4 wv = *(const float4*)(wr + it * 16);
            const float4 xv = *(const float4*)&hx[it * 16 + ks * 4];
            p += wv.x * xv.x + wv.y * xv.y + wv.z * xv.z + wv.w * xv.w;
        }
        part[ks * NH + nn] = p;
    }
    __syncthreads();
    if (t < NH)
        hy[t] = fmaxf(ub2[t] + part[t] + part[NH + t] + part[2 * NH + t] + part[3 * NH + t], 0.f);
    __syncthreads();
    // L3: K=128, no relu -> zout + hz
    {
        const float* wr = uW3 + (size_t)nn * NH + ks * 4;
        float p = 0.f;
        #pragma unroll
        for (int it = 0; it < 8; ++it) {
            const float4 wv = *(const float4*)(wr + it * 16);
            const float4 xv = *(const float4*)&hy[it * 16 + ks * 4];
            p += wv.x * xv.x + wv.y * xv.y + wv.z * xv.z + wv.w * xv.w;
        }
        part[ks * NH + nn] = p;
    }
    __syncthreads();
    if (t < NH) {
        const float v = ub3[t] + part[t] + part[NH + t] + part[2 * NH + t] + part[3 * NH + t];
        zout[(size_t)i * NH + t] = v;
        hz[t] = v;
    }
    if (!do_ab) return;
    __syncthreads();
    // ab: A = z@Wi^T, B = z@Wj^T (K=128, row stride 257 -> dword loads)
    {
        const float* pr = msgW1n + (size_t)nn * 257;
        float pa = 0.f, pb = 0.f;
        #pragma unroll
        for (int it = 0; it < 8; ++it) {
            #pragma unroll
            for (int j = 0; j < 4; ++j) {
                const int k = it * 16 + ks * 4 + j;
                const float x = hz[k];
                pa += x * pr[k];
                pb += x * pr[NH + k];
            }
        }
        part[ks * NH + nn] = pa;
        part2[ks * NH + nn] = pb;
    }
    __syncthreads();
    if (t < NH) {
        An[(size_t)i * NH + t] = part[t] + part[NH + t] + part[2 * NH + t] + part[3 * NH + t];
        Bn[(size_t)i * NH + t] = part2[t] + part2[NH + t] + part2[2 * NH + t] + part2[3 * NH + t];
    }
}

// ---------------------------------------------------------------- host ------
extern "C" void kernel_launch(void* const* d_in, const int* in_sizes, int n_in,
                              void* d_out, int out_size, void* d_ws, size_t ws_size,
                              hipStream_t stream) {
    fp32p obs   = (fp32p)d_in[0];
    fp32p pos   = (fp32p)d_in[1];
    fp32p encW1 = (fp32p)d_in[2];  fp32p encb1 = (fp32p)d_in[3];
    fp32p encW2 = (fp32p)d_in[4];  fp32p encb2 = (fp32p)d_in[5];
    fp32p encW3 = (fp32p)d_in[6];  fp32p encb3 = (fp32p)d_in[7];
    fp32p msgW1 = (fp32p)d_in[8];  fp32p msgb1 = (fp32p)d_in[9];
    fp32p msgW2 = (fp32p)d_in[10]; fp32p msgb2 = (fp32p)d_in[11];
    fp32p msgW3 = (fp32p)d_in[12]; fp32p msgb3 = (fp32p)d_in[13];
    fp32p updW1 = (fp32p)d_in[14]; fp32p updb1 = (fp32p)d_in[15];
    fp32p updW2 = (fp32p)d_in[16]; fp32p updb2 = (fp32p)d_in[17];
    fp32p updW3 = (fp32p)d_in[18]; fp32p updb3 = (fp32p)d_in[19];

    // workspace (fp32): zA | zB | A0 | B0 | A1 | B1  (1.5 MB)
    float* ws = (float*)d_ws;
    float* zA = ws;
    float* zB = zA + NA * NH;
    float* A0 = zB + NA * NH;
    float* B0 = A0 + NA * NH;
    float* A1 = B0 + NA * NH;
    float* B1 = A1 + NA * NH;

    enc_ab_kernel<<<NA, 512, 0, stream>>>(obs, encW1, encb1, encW2, encb2,
                                          encW3, encb3, msgW1, zA, A0, B0);

    float* zin = zA;  float* zout = zB;
    float* Ac = A0;   float* Bc = B0;
    float* An = A1;   float* Bn = B1;
    for (int l = 0; l < 3; ++l) {
        const int do_ab = (l < 2);
        float* dst = (l == 2) ? (float*)d_out : zout;
        msg_upd_kernel<<<NA, 512, 0, stream>>>(Ac, Bc, pos, zin,
            msgW1 + (size_t)l * 128 * 257, msgb1 + l * 128,
            msgW2 + (size_t)l * 128 * 128, msgb2 + l * 128,
            msgW3 + (size_t)l * 128 * 128, msgb3 + l * 128,
            updW1 + (size_t)l * 256 * 128, updb1 + l * 128,
            updW2 + (size_t)l * 128 * 128, updb2 + l * 128,
            updW3 + (size_t)l * 128 * 128, updb3 + l * 128,
            msgW1 + (size_t)(l + 1 < 3 ? l + 1 : 0) * 128 * 257, do_ab,
            dst, An, Bn);
        float* tmp;
        tmp = zin; zin = zout; zout = tmp;
        tmp = Ac; Ac = An; An = tmp;
        tmp = Bc; Bc = Bn; Bn = tmp;
    }
}